// Round 13
// baseline (141.640 us; speedup 1.0000x reference)
//
#include <hip/hip_runtime.h>
#include <hip/hip_bf16.h>
#include <stdint.h>

using bf16x8 = __attribute__((ext_vector_type(8))) __bf16;
using f32x4  = __attribute__((ext_vector_type(4))) float;
using i32x4  = __attribute__((ext_vector_type(4))) int;

#define GBM 128
#define GBN 128
#define GBK 64
#define PROWS 8
// Fragment-major tile layout (per 128-row/col band, per 64-k tile):
//   unit u = (hi*8 + c8)*16 + lo   (hi = row>>4, lo = row&15, c8 = k-octet 0..7)
//   elem offset = u*8 ; tile stride = 8192 elems (16 KB)
// A wave fragment (hi = wr*4+m, c8 = l4 [+4], lo = l15) is 64 lanes x 16B
// fully contiguous => one coalesced global_load_dwordx4 per fragment.

// ---- pack B: 8 whole rows per block, sequential reads, fragment-major writes ----
__global__ __launch_bounds__(256)
void pack_rows(const int* __restrict__ qw, const float* __restrict__ scales,
               __bf16* __restrict__ wsB, int K, int NG, int nT) {
  const int tid = threadIdx.x;
  const int rloc = tid >> 5;
  const int ubase = tid & 31;
  const int n = blockIdx.x * PROWS + rloc;
  const int p = n >> 7;                      // 128-col panel
  const int c = n & 127;
  const int chi = c >> 4, clo = c & 15;
  const float* srow = scales + (size_t)n * NG;
  const int* qrow = qw + (size_t)n * K;
  __bf16* pb = wsB + (size_t)p * nT * 8192;

#pragma unroll
  for (int j = 0; j < 16; ++j) {
    const int cu = ubase + j * 32;           // k-octet 0..511 (sequential reads)
    const i32x4* src = reinterpret_cast<const i32x4*>(qrow + cu * 8);
    i32x4 q0 = src[0], q1 = src[1];
    const float s = srow[cu >> 4];           // GS=128 => 16 octets/group
    const int t  = cu >> 3;
    const int c8 = cu & 7;
    const int u  = (chi * 8 + c8) * 16 + clo;
    bf16x8 w;
    w[0] = (__bf16)((float)q0[0] * s); w[1] = (__bf16)((float)q0[1] * s);
    w[2] = (__bf16)((float)q0[2] * s); w[3] = (__bf16)((float)q0[3] * s);
    w[4] = (__bf16)((float)q1[0] * s); w[5] = (__bf16)((float)q1[1] * s);
    w[6] = (__bf16)((float)q1[2] * s); w[7] = (__bf16)((float)q1[3] * s);
    *reinterpret_cast<bf16x8*>(pb + (size_t)t * 8192 + u * 8) = w;
  }
}

// ---- pack A: x fp32 -> bf16, fragment-major [band][t][u] ----
__global__ __launch_bounds__(256)
void xcvt_p(const float* __restrict__ x, __bf16* __restrict__ wsA, int K, int nT) {
  const int U  = blockIdx.x * 256 + threadIdx.x;
  const int uu = U & 1023;                   // unit within tile
  const int tt = (U >> 10) % nT;
  const int bb = (U >> 10) / nT;             // 128-row band
  const int hi = uu >> 7;
  const int c8 = (uu >> 4) & 7;
  const int lo = uu & 15;
  const int row = hi * 16 + lo;
  const f32x4* src = reinterpret_cast<const f32x4*>(
      x + (size_t)(bb * 128 + row) * K + tt * GBK + c8 * 8);
  f32x4 a = src[0], b = src[1];
  bf16x8 w;
  w[0] = (__bf16)a[0]; w[1] = (__bf16)a[1]; w[2] = (__bf16)a[2]; w[3] = (__bf16)a[3];
  w[4] = (__bf16)b[0]; w[5] = (__bf16)b[1]; w[6] = (__bf16)b[2]; w[7] = (__bf16)b[3];
  *reinterpret_cast<bf16x8*>(wsA + (size_t)U * 8) = w;
}

// ---- GEMM, zero LDS, zero barriers: direct coalesced fragment streaming ----
__global__ __launch_bounds__(256, 2)
void gemm_nolds(const __bf16* __restrict__ wsA, const __bf16* __restrict__ wsB,
                const float* __restrict__ bias, float* __restrict__ out,
                int N, int K, int gy) {
  const int tid  = threadIdx.x;
  const int lane = tid & 63;
  const int wv   = tid >> 6;            // 4 waves
  const int wr   = wv >> 1;             // 0..1 (M half)
  const int wc   = wv & 1;              // 0..1 (N half)
  const int l15  = lane & 15;
  const int l4   = lane >> 4;

  // XCD-chunked mapping (grid 344 = 8*43), by-innermost: co-panel same XCD
  int wgid = blockIdx.x;
  if ((gridDim.x & 7) == 0) {
    const int q = gridDim.x >> 3;
    wgid = (blockIdx.x & 7) * q + (blockIdx.x >> 3);
  }
  const int bx = wgid / gy;
  const int by = wgid % gy;

  const int nT = K / GBK;               // 64

  // per-lane fragment bases (elems): + t*8192 per tile, + hi*1024, + kk*512
  const __bf16* Abase = wsA + (size_t)by * nT * 8192 + l4 * 128 + l15 * 8;
  const __bf16* Bbase = wsB + (size_t)bx * nT * 8192 + l4 * 128 + l15 * 8;

  f32x4 acc[4][4];
#pragma unroll
  for (int m = 0; m < 4; ++m)
#pragma unroll
    for (int n = 0; n < 4; ++n) acc[m][n] = (f32x4)0.0f;

  bf16x8 a0[4][2], b0[4][2], a1[4][2], b1[4][2];

  auto LOAD = [&](bf16x8 (&a)[4][2], bf16x8 (&b)[4][2], int t) {
    const __bf16* At = Abase + (size_t)t * 8192 + (wr * 4) * 1024;
    const __bf16* Bt = Bbase + (size_t)t * 8192 + (wc * 4) * 1024;
#pragma unroll
    for (int m = 0; m < 4; ++m)
#pragma unroll
      for (int kk = 0; kk < 2; ++kk) {
        a[m][kk] = *reinterpret_cast<const bf16x8*>(At + m * 1024 + kk * 512);
        b[m][kk] = *reinterpret_cast<const bf16x8*>(Bt + m * 1024 + kk * 512);
      }
  };
  auto MFMA = [&](const bf16x8 (&a)[4][2], const bf16x8 (&b)[4][2]) {
#pragma unroll
    for (int kk = 0; kk < 2; ++kk)
#pragma unroll
      for (int m = 0; m < 4; ++m)
#pragma unroll
        for (int n = 0; n < 4; ++n)
          acc[m][n] = __builtin_amdgcn_mfma_f32_16x16x32_bf16(a[m][kk], b[n][kk],
                                                              acc[m][n], 0, 0, 0);
  };

  LOAD(a0, b0, 0);
  for (int t = 0; t < nT; t += 2) {
    if (t + 1 < nT) LOAD(a1, b1, t + 1);
    MFMA(a0, b0);
    if (t + 2 < nT) LOAD(a0, b0, t + 2);
    if (t + 1 < nT) MFMA(a1, b1);
  }

  // epilogue: D row = l4*4 + r, col = l15 (verified layout)
  const int tileM = by * GBM, tileN = bx * GBN;
#pragma unroll
  for (int n = 0; n < 4; ++n) {
    const int col = tileN + wc * 64 + n * 16 + l15;
    const float bv = bias[col];
#pragma unroll
    for (int m = 0; m < 4; ++m) {
      const int rbase = tileM + wr * 64 + m * 16 + l4 * 4;
#pragma unroll
      for (int r = 0; r < 4; ++r)
        out[(size_t)(rbase + r) * N + col] = acc[m][n][r] + bv;
    }
  }
}

// ======================= last-resort fallback (no ws) =======================
#define FBM 128
#define FBN 128
#define FBK 64
__global__ __launch_bounds__(256)
void gptq_gemm_fb(const float* __restrict__ x, const int* __restrict__ qw,
                  const float* __restrict__ scales, const float* __restrict__ bias,
                  float* __restrict__ out, int M, int N, int K, int NG, int GS) {
  __shared__ __bf16 lds_a[FBM * FBK];
  __shared__ __bf16 lds_b[FBN * FBK];
  const int tid = threadIdx.x, lane = tid & 63, wave = tid >> 6;
  const int wr = wave >> 1, wc = wave & 1;
  const int tileM = blockIdx.y * FBM, tileN = blockIdx.x * FBN;
  const int l15 = lane & 15, l4 = lane >> 4;
  f32x4 acc[4][4];
#pragma unroll
  for (int m = 0; m < 4; ++m)
#pragma unroll
    for (int n = 0; n < 4; ++n) acc[m][n] = (f32x4)0.0f;
  for (int k0 = 0; k0 < K; k0 += FBK) {
    const int g = k0 / GS;
#pragma unroll
    for (int i = 0; i < 4; ++i) {
      int u = i * 256 + tid, row = u >> 3, c8 = u & 7;
      const f32x4* src = reinterpret_cast<const f32x4*>(x + (size_t)(tileM + row) * K + k0 + c8 * 8);
      f32x4 v0 = src[0], v1 = src[1];
      bf16x8 w;
      w[0]=(__bf16)v0[0]; w[1]=(__bf16)v0[1]; w[2]=(__bf16)v0[2]; w[3]=(__bf16)v0[3];
      w[4]=(__bf16)v1[0]; w[5]=(__bf16)v1[1]; w[6]=(__bf16)v1[2]; w[7]=(__bf16)v1[3];
      int slot = c8 ^ (row & 7);
      *reinterpret_cast<bf16x8*>(&lds_a[row * FBK + slot * 8]) = w;
    }
#pragma unroll
    for (int i = 0; i < 4; ++i) {
      int u = i * 256 + tid, row = u >> 3, c8 = u & 7;
      int gn = tileN + row;
      const i32x4* src = reinterpret_cast<const i32x4*>(qw + (size_t)gn * K + k0 + c8 * 8);
      i32x4 q0 = src[0], q1 = src[1];
      float s = scales[gn * NG + g];
      bf16x8 w;
      w[0]=(__bf16)((float)q0[0]*s); w[1]=(__bf16)((float)q0[1]*s);
      w[2]=(__bf16)((float)q0[2]*s); w[3]=(__bf16)((float)q0[3]*s);
      w[4]=(__bf16)((float)q1[0]*s); w[5]=(__bf16)((float)q1[1]*s);
      w[6]=(__bf16)((float)q1[2]*s); w[7]=(__bf16)((float)q1[3]*s);
      int slot = c8 ^ (row & 7);
      *reinterpret_cast<bf16x8*>(&lds_b[row * FBK + slot * 8]) = w;
    }
    __syncthreads();
#pragma unroll
    for (int kk = 0; kk < FBK; kk += 32) {
      bf16x8 af[4], bfr[4];
#pragma unroll
      for (int m = 0; m < 4; ++m) {
        int row = wr * 64 + m * 16 + l15, slot = ((kk >> 3) + l4) ^ (row & 7);
        af[m] = *reinterpret_cast<const bf16x8*>(&lds_a[row * FBK + slot * 8]);
      }
#pragma unroll
      for (int n = 0; n < 4; ++n) {
        int row = wc * 64 + n * 16 + l15, slot = ((kk >> 3) + l4) ^ (row & 7);
        bfr[n] = *reinterpret_cast<const bf16x8*>(&lds_b[row * FBK + slot * 8]);
      }
#pragma unroll
      for (int m = 0; m < 4; ++m)
#pragma unroll
        for (int n = 0; n < 4; ++n)
          acc[m][n] = __builtin_amdgcn_mfma_f32_16x16x32_bf16(af[m], bfr[n], acc[m][n], 0, 0, 0);
    }
    __syncthreads();
  }
#pragma unroll
  for (int n = 0; n < 4; ++n) {
    int coln = tileN + wc * 64 + n * 16 + l15;
    float bv = bias[coln];
#pragma unroll
    for (int m = 0; m < 4; ++m) {
      int rbase = tileM + wr * 64 + m * 16 + l4 * 4;
#pragma unroll
      for (int r = 0; r < 4; ++r)
        out[(size_t)(rbase + r) * N + coln] = acc[m][n][r] + bv;
    }
  }
}

extern "C" void kernel_launch(void* const* d_in, const int* in_sizes, int n_in,
                              void* d_out, int out_size, void* d_ws, size_t ws_size,
                              hipStream_t stream) {
  const float* x      = (const float*)d_in[0];
  const int*   qw     = (const int*)d_in[1];
  const float* scales = (const float*)d_in[2];
  const float* bias   = (const float*)d_in[3];
  float*       out    = (float*)d_out;

  const int OUT = in_sizes[3];            // 11008
  const int IN  = in_sizes[1] / OUT;      // 4096
  const int M   = in_sizes[0] / IN;       // 512
  const int NG  = in_sizes[2] / OUT;      // 32
  const int GS  = IN / NG;                // 128

  const size_t needB = (size_t)OUT * IN * sizeof(__bf16);   // 90.2 MB
  const size_t needA = (size_t)M * IN * sizeof(__bf16);     // 4.2 MB
  const int nT = IN / GBK;                                  // 64

  const bool ok_packed =
      (ws_size >= needB + needA) && (M % GBM == 0) && (OUT % GBN == 0) &&
      (IN % (2 * GBK) == 0) && (GS == 128) && (NG == IN / 128) &&
      (OUT % PROWS == 0);

  if (ok_packed) {
    __bf16* wsB = (__bf16*)d_ws;
    __bf16* wsA = (__bf16*)((char*)d_ws + needB);
    pack_rows<<<OUT / PROWS, 256, 0, stream>>>(qw, scales, wsB, IN, NG, nT);
    const int bands = M / 128;            // 4
    const int unitsA = bands * nT * 1024;
    xcvt_p<<<unitsA / 256, 256, 0, stream>>>(x, wsA, IN, nT);
    const int gx = OUT / GBN;             // 86
    const int gy = M / GBM;               // 4
    gemm_nolds<<<gx * gy, 256, 0, stream>>>(wsA, wsB, bias, out, OUT, IN, gy);
  } else {
    dim3 grid(OUT / FBN, M / FBM);
    gptq_gemm_fb<<<grid, 256, 0, stream>>>(x, qw, scales, bias, out, M, OUT, IN, NG, GS);
  }
}

// Round 14
// 136.397 us; speedup vs baseline: 1.0384x; 1.0384x over previous
//
#include <hip/hip_runtime.h>
#include <hip/hip_bf16.h>
#include <stdint.h>

using bf16x8 = __attribute__((ext_vector_type(8))) __bf16;
using f32x4  = __attribute__((ext_vector_type(4))) float;
using i32x4  = __attribute__((ext_vector_type(4))) int;

#define GBM 256
#define GBN 128
#define GBK 64
#define GTHR 512   // 8 waves, 4(M) x 2(N); wave tile 64x64, acc 4x4
#define PROWS 8

__device__ __forceinline__ void gload_lds16(const void* g, void* l) {
  __builtin_amdgcn_global_load_lds((const __attribute__((address_space(1))) void*)g,
                                   (__attribute__((address_space(3))) void*)l,
                                   16, 0, 0);
}

// ---- pack B (row-streaming, R9-proven): 8 whole rows/block, sequential reads ----
// Panel p = 128 cols; tile t = [128 rows][8 slots];
// unit(row,sl) holds W[row][(sl^(row&7))*8 + t*64 ..+8]
__global__ __launch_bounds__(256)
void pack_rows(const int* __restrict__ qw, const float* __restrict__ scales,
               __bf16* __restrict__ wsB, int K, int NG, int nT) {
  const int tid = threadIdx.x;
  const int rloc = tid >> 5;
  const int ubase = tid & 31;
  const int n = blockIdx.x * PROWS + rloc;
  const int p = n >> 7;
  const int rit = n & 127;
  const int rb7 = rit & 7;
  const float* srow = scales + (size_t)n * NG;
  const int* qrow = qw + (size_t)n * K;
  __bf16* base = wsB + (size_t)p * nT * (128 * GBK) + (size_t)rit * GBK;

#pragma unroll
  for (int j = 0; j < 16; ++j) {
    const int cu = ubase + j * 32;           // k-unit 0..511
    const i32x4* src = reinterpret_cast<const i32x4*>(qrow + cu * 8);
    i32x4 q0 = src[0], q1 = src[1];
    const float s = srow[cu >> 4];           // GS=128 => 16 units/group
    const int t  = cu >> 3;                  // 8 units per 64-k tile
    const int sl = (cu & 7) ^ rb7;
    bf16x8 w;
    w[0] = (__bf16)((float)q0[0] * s); w[1] = (__bf16)((float)q0[1] * s);
    w[2] = (__bf16)((float)q0[2] * s); w[3] = (__bf16)((float)q0[3] * s);
    w[4] = (__bf16)((float)q1[0] * s); w[5] = (__bf16)((float)q1[1] * s);
    w[6] = (__bf16)((float)q1[2] * s); w[7] = (__bf16)((float)q1[3] * s);
    *reinterpret_cast<bf16x8*>(base + (size_t)t * (128 * GBK) + sl * 8) = w;
  }
}

// ---- pack A (R9-proven): x fp32 -> bf16, 128-row bands, same swizzle ----
__global__ __launch_bounds__(256)
void xcvt_p(const float* __restrict__ x, __bf16* __restrict__ wsA, int K, int nT) {
  const int U  = blockIdx.x * 256 + threadIdx.x;
  const int uu = U & 1023;
  const int tt = (U >> 10) % nT;
  const int bb = (U >> 10) / nT;             // 128-row band
  const int row = uu >> 3, slot = uu & 7;
  const int c8 = slot ^ (row & 7);
  const f32x4* src = reinterpret_cast<const f32x4*>(
      x + (size_t)(bb * 128 + row) * K + tt * GBK + c8 * 8);
  f32x4 a = src[0], b = src[1];
  bf16x8 w;
  w[0] = (__bf16)a[0]; w[1] = (__bf16)a[1]; w[2] = (__bf16)a[2]; w[3] = (__bf16)a[3];
  w[4] = (__bf16)b[0]; w[5] = (__bf16)b[1]; w[6] = (__bf16)b[2]; w[7] = (__bf16)b[3];
  *reinterpret_cast<bf16x8*>(wsA + (size_t)U * 8) = w;
}

// ---- packed GEMM: 256x128 tile, 8 waves, 2-deep vmcnt(6); bx-inner XCD chunk ----
__global__ __launch_bounds__(GTHR, 1)
void gemm_packed(const __bf16* __restrict__ wsA, const __bf16* __restrict__ wsB,
                 const float* __restrict__ bias, float* __restrict__ out,
                 int N, int K, int gx) {
  const int tid  = threadIdx.x;
  const int lane = tid & 63;
  const int wv   = tid >> 6;            // 0..7
  const int wr   = wv >> 1;             // 0..3 (M)
  const int wc   = wv & 1;              // 0..1 (N)

  // Bijective XCD chunking (m204): contiguous wgids per XCD; bx-innermost
  // decode => all blocks on one XCD share ONE A band (L2-resident).
  const int nwg = gridDim.x;
  const int q8  = nwg >> 3, r8 = nwg & 7;
  const int xcd = blockIdx.x & 7, pos = blockIdx.x >> 3;
  const int wgid = (xcd < r8 ? xcd * (q8 + 1) : r8 * (q8 + 1) + (xcd - r8) * q8) + pos;
  const int by = wgid / gx;
  const int bx = wgid % gx;

  const int l15 = lane & 15;
  const int l4  = lane >> 4;
  const int nT  = K / GBK;              // 64

  __shared__ __bf16 As[2][GBM * GBK];   // 2 x 32 KiB
  __shared__ __bf16 Bs[2][GBN * GBK];   // 2 x 16 KiB

  const size_t bandStride = (size_t)nT * (128 * GBK);
  const __bf16* a0base = wsA + (size_t)(2 * by)     * bandStride;
  const __bf16* a1base = wsA + (size_t)(2 * by + 1) * bandStride;
  const __bf16* bbase  = wsB + (size_t)bx * bandStride;

  f32x4 acc[4][4];
#pragma unroll
  for (int m = 0; m < 4; ++m)
#pragma unroll
    for (int n = 0; n < 4; ++n) acc[m][n] = (f32x4)0.0f;

  // 6 gload_lds16 per thread per stage: A band0 x2, A band1 x2, B x2
  auto STAGE = [&](int buf, int t) {
    const __bf16* a0 = a0base + (size_t)t * (128 * GBK);
    const __bf16* a1 = a1base + (size_t)t * (128 * GBK);
    const __bf16* b  = bbase  + (size_t)t * (128 * GBK);
#pragma unroll
    for (int i = 0; i < 2; ++i) {
      const int ub = (i * 8 + wv) * 64;               // units 0..1023
      gload_lds16(a0 + (size_t)(ub + lane) * 8, &As[buf][ub * 8]);
      gload_lds16(a1 + (size_t)(ub + lane) * 8, &As[buf][8192 + ub * 8]);
      gload_lds16(b  + (size_t)(ub + lane) * 8, &Bs[buf][ub * 8]);
    }
  };

  auto MF = [&](const __bf16* A_, const __bf16* B_) {
#pragma unroll
    for (int kk = 0; kk < 2; ++kk) {
      const int c8 = kk * 4 + l4;
      bf16x8 af[4], bf_[4];
#pragma unroll
      for (int m = 0; m < 4; ++m) {
        const int row = wr * 64 + m * 16 + l15;       // 0..255
        const int slot = c8 ^ (row & 7);
        af[m] = *reinterpret_cast<const bf16x8*>(&A_[row * GBK + slot * 8]);
      }
#pragma unroll
      for (int n = 0; n < 4; ++n) {
        const int col = wc * 64 + n * 16 + l15;       // 0..127
        const int slot = c8 ^ (col & 7);
        bf_[n] = *reinterpret_cast<const bf16x8*>(&B_[col * GBK + slot * 8]);
      }
#pragma unroll
      for (int m = 0; m < 4; ++m)
#pragma unroll
        for (int n = 0; n < 4; ++n)
          acc[m][n] = __builtin_amdgcn_mfma_f32_16x16x32_bf16(af[m], bf_[n], acc[m][n], 0, 0, 0);
    }
  };

  STAGE(0, 0);
  STAGE(1, 1);                           // 12 VMEM outstanding per thread

  int cur = 0;
  for (int t = 0; t < nT; ++t) {
    if (t + 1 < nT) { asm volatile("s_waitcnt vmcnt(6)" ::: "memory"); }
    else            { asm volatile("s_waitcnt vmcnt(0)" ::: "memory"); }
    __builtin_amdgcn_s_barrier();
    __builtin_amdgcn_sched_barrier(0);
    MF(As[cur], Bs[cur]);
    __builtin_amdgcn_sched_barrier(0);
    __builtin_amdgcn_s_barrier();
    if (t + 2 < nT) STAGE(cur, t + 2);
    __builtin_amdgcn_sched_barrier(0);
    cur ^= 1;
  }

  // epilogue: D row = l4*4 + r, col = l15 (verified layout)
  const int tileM = by * GBM, tileN = bx * GBN;
#pragma unroll
  for (int n = 0; n < 4; ++n) {
    const int col = tileN + wc * 64 + n * 16 + l15;
    const float bv = bias[col];
#pragma unroll
    for (int m = 0; m < 4; ++m) {
      const int rbase = tileM + wr * 64 + m * 16 + l4 * 4;
#pragma unroll
      for (int r = 0; r < 4; ++r)
        out[(size_t)(rbase + r) * N + col] = acc[m][n][r] + bv;
    }
  }
}

// ======================= last-resort fallback (no ws) =======================
#define FBM 128
#define FBN 128
#define FBK 64
__global__ __launch_bounds__(256)
void gptq_gemm_fb(const float* __restrict__ x, const int* __restrict__ qw,
                  const float* __restrict__ scales, const float* __restrict__ bias,
                  float* __restrict__ out, int M, int N, int K, int NG, int GS) {
  __shared__ __bf16 lds_a[FBM * FBK];
  __shared__ __bf16 lds_b[FBN * FBK];
  const int tid = threadIdx.x, lane = tid & 63, wave = tid >> 6;
  const int wr = wave >> 1, wc = wave & 1;
  const int tileM = blockIdx.y * FBM, tileN = blockIdx.x * FBN;
  const int l15 = lane & 15, l4 = lane >> 4;
  f32x4 acc[4][4];
#pragma unroll
  for (int m = 0; m < 4; ++m)
#pragma unroll
    for (int n = 0; n < 4; ++n) acc[m][n] = (f32x4)0.0f;
  for (int k0 = 0; k0 < K; k0 += FBK) {
    const int g = k0 / GS;
#pragma unroll
    for (int i = 0; i < 4; ++i) {
      int u = i * 256 + tid, row = u >> 3, c8 = u & 7;
      const f32x4* src = reinterpret_cast<const f32x4*>(x + (size_t)(tileM + row) * K + k0 + c8 * 8);
      f32x4 v0 = src[0], v1 = src[1];
      bf16x8 w;
      w[0]=(__bf16)v0[0]; w[1]=(__bf16)v0[1]; w[2]=(__bf16)v0[2]; w[3]=(__bf16)v0[3];
      w[4]=(__bf16)v1[0]; w[5]=(__bf16)v1[1]; w[6]=(__bf16)v1[2]; w[7]=(__bf16)v1[3];
      int slot = c8 ^ (row & 7);
      *reinterpret_cast<bf16x8*>(&lds_a[row * FBK + slot * 8]) = w;
    }
#pragma unroll
    for (int i = 0; i < 4; ++i) {
      int u = i * 256 + tid, row = u >> 3, c8 = u & 7;
      int gn = tileN + row;
      const i32x4* src = reinterpret_cast<const i32x4*>(qw + (size_t)gn * K + k0 + c8 * 8);
      i32x4 q0 = src[0], q1 = src[1];
      float s = scales[gn * NG + g];
      bf16x8 w;
      w[0]=(__bf16)((float)q0[0]*s); w[1]=(__bf16)((float)q0[1]*s);
      w[2]=(__bf16)((float)q0[2]*s); w[3]=(__bf16)((float)q0[3]*s);
      w[4]=(__bf16)((float)q1[0]*s); w[5]=(__bf16)((float)q1[1]*s);
      w[6]=(__bf16)((float)q1[2]*s); w[7]=(__bf16)((float)q1[3]*s);
      int slot = c8 ^ (row & 7);
      *reinterpret_cast<bf16x8*>(&lds_b[row * FBK + slot * 8]) = w;
    }
    __syncthreads();
#pragma unroll
    for (int kk = 0; kk < FBK; kk += 32) {
      bf16x8 af[4], bfr[4];
#pragma unroll
      for (int m = 0; m < 4; ++m) {
        int row = wr * 64 + m * 16 + l15, slot = ((kk >> 3) + l4) ^ (row & 7);
        af[m] = *reinterpret_cast<const bf16x8*>(&lds_a[row * FBK + slot * 8]);
      }
#pragma unroll
      for (int n = 0; n < 4; ++n) {
        int row = wc * 64 + n * 16 + l15, slot = ((kk >> 3) + l4) ^ (row & 7);
        bfr[n] = *reinterpret_cast<const bf16x8*>(&lds_b[row * FBK + slot * 8]);
      }
#pragma unroll
      for (int m = 0; m < 4; ++m)
#pragma unroll
        for (int n = 0; n < 4; ++n)
          acc[m][n] = __builtin_amdgcn_mfma_f32_16x16x32_bf16(af[m], bfr[n], acc[m][n], 0, 0, 0);
    }
    __syncthreads();
  }
#pragma unroll
  for (int n = 0; n < 4; ++n) {
    int coln = tileN + wc * 64 + n * 16 + l15;
    float bv = bias[coln];
#pragma unroll
    for (int m = 0; m < 4; ++m) {
      int rbase = tileM + wr * 64 + m * 16 + l4 * 4;
#pragma unroll
      for (int r = 0; r < 4; ++r)
        out[(size_t)(rbase + r) * N + coln] = acc[m][n][r] + bv;
    }
  }
}

extern "C" void kernel_launch(void* const* d_in, const int* in_sizes, int n_in,
                              void* d_out, int out_size, void* d_ws, size_t ws_size,
                              hipStream_t stream) {
  const float* x      = (const float*)d_in[0];
  const int*   qw     = (const int*)d_in[1];
  const float* scales = (const float*)d_in[2];
  const float* bias   = (const float*)d_in[3];
  float*       out    = (float*)d_out;

  const int OUT = in_sizes[3];            // 11008
  const int IN  = in_sizes[1] / OUT;      // 4096
  const int M   = in_sizes[0] / IN;       // 512
  const int NG  = in_sizes[2] / OUT;      // 32
  const int GS  = IN / NG;                // 128

  const size_t needB = (size_t)OUT * IN * sizeof(__bf16);   // 90.2 MB
  const size_t needA = (size_t)M * IN * sizeof(__bf16);     // 4.2 MB
  const int nT = IN / GBK;                                  // 64

  const bool ok_packed =
      (ws_size >= needB + needA) && (M % GBM == 0) && (OUT % GBN == 0) &&
      (IN % (2 * GBK) == 0) && (GS == 128) && (NG == IN / 128) &&
      (OUT % PROWS == 0);

  if (ok_packed) {
    __bf16* wsB = (__bf16*)d_ws;
    __bf16* wsA = (__bf16*)((char*)d_ws + needB);
    pack_rows<<<OUT / PROWS, 256, 0, stream>>>(qw, scales, wsB, IN, NG, nT);
    const int bands = M / 128;            // 4
    const int unitsA = bands * nT * 1024;
    xcvt_p<<<unitsA / 256, 256, 0, stream>>>(x, wsA, IN, nT);
    const int gx = OUT / GBN;             // 86
    const int gy = M / GBM;               // 2
    gemm_packed<<<gx * gy, GTHR, 0, stream>>>(wsA, wsB, bias, out, OUT, IN, gx);
  } else {
    dim3 grid(OUT / FBN, M / FBM);
    gptq_gemm_fb<<<grid, 256, 0, stream>>>(x, qw, scales, bias, out, M, OUT, IN, NG, GS);
  }
}